// Round 5
// baseline (11801.047 us; speedup 1.0000x reference)
//
#include <hip/hip_runtime.h>
#include <math.h>

#define T_STEPS 1024
#define NB 64        // batch
#define NH 512       // hidden
#define NI 256       // input

#define NGRP 4           // batch groups
#define BPG 16           // batches per group (= MFMA M)
#define WGS_PER_GRP 4    // h-split WGs per group
#define WAVES_PER_GRP 32 // 4 WGs x 8 waves: barrier signals per wave
#define HPWG 128         // h columns per WG
#define HPWAVE 16        // h columns per wave (one 16x16 MFMA tile)

// d_ws layout
#define WS_YBUF_OFF 4096                       // double-buffered bf16 y: 2*64*512
#define WS_INIT_BYTES (WS_YBUF_OFF + NB*NH*2)  // counters + y slot 0 zeroed

typedef short short8 __attribute__((ext_vector_type(8)));
typedef float f32x4 __attribute__((ext_vector_type(4)));

__device__ __forceinline__ unsigned short f32_to_bf16(float x) {
    unsigned u = __float_as_uint(x);
    u += 0x7FFFu + ((u >> 16) & 1u);   // round-to-nearest-even
    return (unsigned short)(u >> 16);
}

__device__ __forceinline__ float tanh_fast(float x) {
    x = fminf(15.f, fmaxf(-15.f, x));
    const float ex = __expf(-2.f * x);
    return __fdividef(1.f - ex, 1.f + ex);
}

// ---------------------------------------------------------------------------
// Kernel 1: ext[t,b,h] = inputs[t,b,:] @ W_ih[:,h] + b_ih[h], written to d_out.
// (measured ~near f32-VALU peak; untouched this round)
// ---------------------------------------------------------------------------
__global__ __launch_bounds__(256) void ext_gemm_kernel(
    const float* __restrict__ inputs, const float* __restrict__ W_ih,
    const float* __restrict__ b_ih, float* __restrict__ out)
{
    __shared__ float Wt[NI * 64];   // [i][h], 64 KiB
    const int tid    = threadIdx.x;
    const int hgrp   = blockIdx.x & 7;
    const int rowgrp = blockIdx.x >> 3;
    const int hbase  = hgrp * 64;
    const long rowbase = (long)rowgrp * 512;

    for (int idx = tid; idx < NI * 64; idx += 256) {
        int i  = idx >> 6;
        int hh = idx & 63;
        Wt[idx] = W_ih[(size_t)i * NH + hbase + hh];
    }
    const int hq = tid & 15;
    const int r  = tid >> 4;
    const float4 bias = *(const float4*)&b_ih[hbase + hq * 4];
    __syncthreads();

    for (int rc = 0; rc < 32; ++rc) {
        const long row = rowbase + rc * 16 + r;
        const float* __restrict__ inrow = inputs + row * NI;
        float ax = 0.f, ay = 0.f, az = 0.f, aw = 0.f;
        #pragma unroll 4
        for (int i = 0; i < NI; i += 4) {
            const float4 a  = *(const float4*)(inrow + i);
            const float4 w0 = *(const float4*)&Wt[(i + 0) * 64 + hq * 4];
            const float4 w1 = *(const float4*)&Wt[(i + 1) * 64 + hq * 4];
            const float4 w2 = *(const float4*)&Wt[(i + 2) * 64 + hq * 4];
            const float4 w3 = *(const float4*)&Wt[(i + 3) * 64 + hq * 4];
            ax += a.x * w0.x + a.y * w1.x + a.z * w2.x + a.w * w3.x;
            ay += a.x * w0.y + a.y * w1.y + a.z * w2.y + a.w * w3.y;
            az += a.x * w0.z + a.y * w1.z + a.z * w2.z + a.w * w3.z;
            aw += a.x * w0.w + a.y * w1.w + a.z * w2.w + a.w * w3.w;
        }
        float4 o = make_float4(ax + bias.x, ay + bias.y, az + bias.z, aw + bias.w);
        *(float4*)&out[row * NH + hbase + hq * 4] = o;
    }
}

// ---------------------------------------------------------------------------
// Kernel 2: MFMA recurrent scan. 16 WGs x 512 threads.
//   grp = bid & 3 (batch group of 16), wgi = bid >> 2 (h slice of 128).
// Each wave owns one 16x16 output tile (16 batches x 16 h), full K=512:
//   - W_hh B-fragments register-resident (16 x short8 = 64 VGPR), loaded once.
//     k-slot mapping myk(g,j)=8g+j is applied identically to A and B
//     fragments, so any internal HW k-permutation cancels in the dot product.
//   - y crosses steps as bf16 in global ybuf (A-frags: 16 x 16B loads/lane).
//   - x,y state f32 in the lane holding the C fragment
//     (C/D layout: col = lane&15 = h, row = (lane>>4)*4 + reg = batch).
// No LDS, no __syncthreads. Per-wave barrier: vmcnt drain -> release
// fetch_add -> e[t+1] prefetch -> relaxed poll (s_sleep) -> acquire fence.
// ---------------------------------------------------------------------------
__global__ __launch_bounds__(512, 2) void horn_recurrent_kernel(
    const float* __restrict__ W_hh, const float* __restrict__ b_hh,
    const float* __restrict__ alpha, const float* __restrict__ omega,
    const float* __restrict__ gamma, const float* __restrict__ v,
    float* __restrict__ out, unsigned short* __restrict__ ybuf,
    unsigned* __restrict__ counters)
{
    const int tid  = threadIdx.x;
    const int wave = tid >> 6;
    const int lane = tid & 63;
    const int g    = lane >> 4;   // 0..3 (k sub-slot / batch quad)
    const int c    = lane & 15;   // h within tile (and A-row batch for loads)

    const int grp   = blockIdx.x & (NGRP - 1);
    const int wgi   = blockIdx.x >> 2;
    const int bbase = grp * BPG;
    const int hbase = wgi * HPWG + wave * HPWAVE;
    const int h     = hbase + c;              // this lane's global h column

    // ---- W_hh -> register-resident B fragments (once) ----
    // slot (kb, g, j) holds W_hh[kb*32 + 8g + j][h], bf16
    short8 wfrag[16];
    #pragma unroll
    for (int kb = 0; kb < 16; ++kb) {
        short8 f;
        #pragma unroll
        for (int j = 0; j < 8; ++j)
            f[j] = (short)f32_to_bf16(W_hh[(size_t)(kb * 32 + 8 * g + j) * NH + h]);
        wfrag[kb] = f;
    }

    const float bhh_r = b_hh[h];
    const float al_r  = alpha[h];
    const float omv   = omega[h];
    const float om2_r = omv * omv;
    const float g2_r  = 2.0f * gamma[h];
    const float v_r   = v[h];
    const float gain  = 0.04419417382415922f;   // 1/sqrt(512)
    const float hdt   = 0.1f;

    unsigned* cnt = counters + grp * 64;   // 256 B spacing per group

    float xs[4] = {0.f, 0.f, 0.f, 0.f};
    float ys[4] = {0.f, 0.f, 0.f, 0.f};
    float ev[4];

    // prologue: prefetch e[0] for this lane's 4 (batch,h) cells
    #pragma unroll
    for (int r = 0; r < 4; ++r)
        ev[r] = out[(size_t)(bbase + 4 * g + r) * NH + h];

    for (int t = 0; t < T_STEPS; ++t) {
        // ---- rec = y(t) @ W_hh : 16 MFMA, A-frags straight from global ----
        const unsigned short* __restrict__ ysrc =
            ybuf + (size_t)(t & 1) * NB * NH + (size_t)(bbase + c) * NH + 8 * g;
        f32x4 acc[4];
        #pragma unroll
        for (int i = 0; i < 4; ++i) acc[i] = (f32x4){0.f, 0.f, 0.f, 0.f};
        #pragma unroll
        for (int kb = 0; kb < 16; ++kb) {
            const short8 afrag = *(const short8*)(ysrc + kb * 32);
            acc[kb & 3] = __builtin_amdgcn_mfma_f32_16x16x32_bf16(
                afrag, wfrag[kb], acc[kb & 3], 0, 0, 0);
        }
        const f32x4 recv = (acc[0] + acc[1]) + (acc[2] + acc[3]);

        // ---- elementwise update (reference order), f32 state in-lane ----
        #pragma unroll
        for (int r = 0; r < 4; ++r) {
            const float rec = recv[r] + bhh_r;
            const float inp = ev[r] + gain * (rec + v_r * xs[r]);
            const float yt  = ys[r] + hdt * (al_r * tanh_fast(inp)
                                             - om2_r * xs[r] - g2_r * ys[r]);
            const float xt  = xs[r] + hdt * yt;
            xs[r] = xt; ys[r] = yt;
        }

        // ---- stores: x over ext slot in d_out, y(t+1) bf16 to other slot ----
        const size_t obase = ((size_t)t * NB + bbase + 4 * g) * NH + h;
        unsigned short* __restrict__ ydst =
            ybuf + (size_t)((t + 1) & 1) * NB * NH + (size_t)(bbase + 4 * g) * NH + h;
        #pragma unroll
        for (int r = 0; r < 4; ++r) {
            out[obase + (size_t)r * NH] = xs[r];
            ydst[(size_t)r * NH] = f32_to_bf16(ys[r]);
        }

        if (t == T_STEPS - 1) break;

        // ---- per-wave group barrier (32 waves) ----
        asm volatile("s_waitcnt vmcnt(0)" ::: "memory");   // stores at L2+
        if (lane == 0)
            __hip_atomic_fetch_add(cnt, 1u, __ATOMIC_RELEASE, __HIP_MEMORY_SCOPE_AGENT);
        // prefetch e[t+1] while polling (private cells, safe pre-barrier)
        #pragma unroll
        for (int r = 0; r < 4; ++r)
            ev[r] = out[obase + (size_t)NB * NH + (size_t)r * NH];
        const unsigned target = (unsigned)WAVES_PER_GRP * (unsigned)(t + 1);
        while (__hip_atomic_load(cnt, __ATOMIC_RELAXED, __HIP_MEMORY_SCOPE_AGENT) < target)
            __builtin_amdgcn_s_sleep(1);
        __builtin_amdgcn_fence(__ATOMIC_ACQUIRE, "agent");  // one inv, then reload y
    }
}

// ---------------------------------------------------------------------------
extern "C" void kernel_launch(void* const* d_in, const int* in_sizes, int n_in,
                              void* d_out, int out_size, void* d_ws, size_t ws_size,
                              hipStream_t stream) {
    const float* inputs = (const float*)d_in[0];
    const float* W_ih   = (const float*)d_in[1];
    const float* b_ih   = (const float*)d_in[2];
    const float* W_hh   = (const float*)d_in[3];
    const float* b_hh   = (const float*)d_in[4];
    const float* alpha  = (const float*)d_in[5];
    const float* omega  = (const float*)d_in[6];
    const float* gamma  = (const float*)d_in[7];
    const float* v      = (const float*)d_in[8];
    float* out = (float*)d_out;

    unsigned* counters   = (unsigned*)d_ws;
    unsigned short* ybuf = (unsigned short*)((char*)d_ws + WS_YBUF_OFF);

    // zero barrier counters + bf16 y slot 0 (d_ws re-poisoned every launch)
    hipMemsetAsync(d_ws, 0, WS_INIT_BYTES, stream);

    // ext = inputs @ W_ih + b_ih, written into d_out (overwritten step-by-step)
    ext_gemm_kernel<<<dim3(1024), dim3(256), 0, stream>>>(inputs, W_ih, b_ih, out);

    // sequential scan: 16 WGs (4 groups x 4 h-slices) x 512 threads
    horn_recurrent_kernel<<<dim3(NGRP * WGS_PER_GRP), dim3(512), 0, stream>>>(
        W_hh, b_hh, alpha, omega, gamma, v, out, ybuf, counters);
}

// Round 7
// 6152.279 us; speedup vs baseline: 1.9182x; 1.9182x over previous
//
#include <hip/hip_runtime.h>
#include <math.h>

#define T_STEPS 1024
#define NB 64        // batch
#define NH 512       // hidden
#define NI 256       // input

#define NGRP 4           // batch groups
#define BPG 16           // batches per group (= MFMA M)
#define WGS_PER_GRP 4    // h-split WGs per group

// d_ws layout
#define WS_YBUF_OFF 4096                       // double-buffered bf16 y: 2*64*512
#define WS_INIT_BYTES (WS_YBUF_OFF + NB*NH*2)  // flags + y slot 0 zeroed

typedef short short8 __attribute__((ext_vector_type(8)));
typedef float f32x4 __attribute__((ext_vector_type(4)));

__device__ __forceinline__ unsigned short f32_to_bf16(float x) {
    unsigned u = __float_as_uint(x);
    u += 0x7FFFu + ((u >> 16) & 1u);   // round-to-nearest-even
    return (unsigned short)(u >> 16);
}

__device__ __forceinline__ float tanh_fast(float x) {
    x = fminf(15.f, fmaxf(-15.f, x));
    const float ex = __expf(-2.f * x);
    return __fdividef(1.f - ex, 1.f + ex);
}

// ---------------------------------------------------------------------------
// Kernel 1: ext[t,b,h] = inputs[t,b,:] @ W_ih[:,h] + b_ih[h], written to d_out.
// ---------------------------------------------------------------------------
__global__ __launch_bounds__(256) void ext_gemm_kernel(
    const float* __restrict__ inputs, const float* __restrict__ W_ih,
    const float* __restrict__ b_ih, float* __restrict__ out)
{
    __shared__ float Wt[NI * 64];   // [i][h], 64 KiB
    const int tid    = threadIdx.x;
    const int hgrp   = blockIdx.x & 7;
    const int rowgrp = blockIdx.x >> 3;
    const int hbase  = hgrp * 64;
    const long rowbase = (long)rowgrp * 512;

    for (int idx = tid; idx < NI * 64; idx += 256) {
        int i  = idx >> 6;
        int hh = idx & 63;
        Wt[idx] = W_ih[(size_t)i * NH + hbase + hh];
    }
    const int hq = tid & 15;
    const int r  = tid >> 4;
    const float4 bias = *(const float4*)&b_ih[hbase + hq * 4];
    __syncthreads();

    for (int rc = 0; rc < 32; ++rc) {
        const long row = rowbase + rc * 16 + r;
        const float* __restrict__ inrow = inputs + row * NI;
        float ax = 0.f, ay = 0.f, az = 0.f, aw = 0.f;
        #pragma unroll 4
        for (int i = 0; i < NI; i += 4) {
            const float4 a  = *(const float4*)(inrow + i);
            const float4 w0 = *(const float4*)&Wt[(i + 0) * 64 + hq * 4];
            const float4 w1 = *(const float4*)&Wt[(i + 1) * 64 + hq * 4];
            const float4 w2 = *(const float4*)&Wt[(i + 2) * 64 + hq * 4];
            const float4 w3 = *(const float4*)&Wt[(i + 3) * 64 + hq * 4];
            ax += a.x * w0.x + a.y * w1.x + a.z * w2.x + a.w * w3.x;
            ay += a.x * w0.y + a.y * w1.y + a.z * w2.y + a.w * w3.y;
            az += a.x * w0.z + a.y * w1.z + a.z * w2.z + a.w * w3.z;
            aw += a.x * w0.w + a.y * w1.w + a.z * w2.w + a.w * w3.w;
        }
        float4 o = make_float4(ax + bias.x, ay + bias.y, az + bias.z, aw + bias.w);
        *(float4*)&out[row * NH + hbase + hq * 4] = o;
    }
}

// ---------------------------------------------------------------------------
// Kernel 2: MFMA recurrent scan. 16 WGs x 512 threads.
//   grp = bid & 3 (16-batch group), wgi = bid >> 2 (128-h slice).
// Wave owns one 16x16 tile (16 batches x 16 h), full K=512.
// W_hh B-fragments live in 16 NAMED short8 locals (w0..w15) — no per-thread
// arrays anywhere (arrays >=256B get demoted to scratch by promote-alloca;
// that was rounds 2/5's 64-VGPR + scratch-reload disaster).
// Barrier: per-WG flag store (no RMW) + single-thread poll of 4 flags.
// ---------------------------------------------------------------------------
__global__ __launch_bounds__(512, 1) void horn_recurrent_kernel(
    const float* __restrict__ W_hh, const float* __restrict__ b_hh,
    const float* __restrict__ alpha, const float* __restrict__ omega,
    const float* __restrict__ gamma, const float* __restrict__ v,
    float* __restrict__ out, unsigned short* __restrict__ ybuf,
    unsigned* __restrict__ flags)
{
    const int tid  = threadIdx.x;
    const int wave = tid >> 6;
    const int lane = tid & 63;
    const int g    = lane >> 4;   // 0..3 (k sub-slot / batch quad)
    const int c    = lane & 15;   // h within tile (A-row batch for loads)

    const int grp   = blockIdx.x & (NGRP - 1);
    const int wgi   = blockIdx.x >> 2;
    const int bbase = grp * BPG;
    const int h     = wgi * 128 + wave * 16 + c;   // global h column

    // ---- W_hh -> 16 named register-resident B fragments (once) ----
    // slot (KB, g, j) holds W_hh[KB*32 + 8g + j][h] as bf16; the k mapping
    // myk(g,j)=8g+j is identical on A and B sides so it cancels in the dot.
    short8 w0, w1, w2, w3, w4, w5, w6, w7, w8, w9, w10, w11, w12, w13, w14, w15;
#define LDW(KB)                                                              \
    {                                                                        \
        const float* wp = W_hh + (size_t)(KB * 32 + 8 * g) * NH + h;         \
        short8 f;                                                            \
        f[0] = (short)f32_to_bf16(wp[0 * NH]);                               \
        f[1] = (short)f32_to_bf16(wp[1 * NH]);                               \
        f[2] = (short)f32_to_bf16(wp[2 * NH]);                               \
        f[3] = (short)f32_to_bf16(wp[3 * NH]);                               \
        f[4] = (short)f32_to_bf16(wp[4 * NH]);                               \
        f[5] = (short)f32_to_bf16(wp[5 * NH]);                               \
        f[6] = (short)f32_to_bf16(wp[6 * NH]);                               \
        f[7] = (short)f32_to_bf16(wp[7 * NH]);                               \
        w##KB = f;                                                           \
    }
    LDW(0)  LDW(1)  LDW(2)  LDW(3)  LDW(4)  LDW(5)  LDW(6)  LDW(7)
    LDW(8)  LDW(9)  LDW(10) LDW(11) LDW(12) LDW(13) LDW(14) LDW(15)
#undef LDW

    const float bhh_r = b_hh[h];
    const float al_r  = alpha[h];
    const float omv   = omega[h];
    const float om2_r = omv * omv;
    const float g2_r  = 2.0f * gamma[h];
    const float v_r   = v[h];
    const float gain  = 0.04419417382415922f;   // 1/sqrt(512)
    const float hdt   = 0.1f;

    // named per-lane state (4 C-rows: batches bbase+4g .. +3)
    float x0 = 0.f, x1 = 0.f, x2 = 0.f, x3 = 0.f;
    float y0 = 0.f, y1 = 0.f, y2 = 0.f, y3 = 0.f;
    float e0, e1, e2, e3;

    // prologue: prefetch e[0]
    {
        const float* ep = out + (size_t)(bbase + 4 * g) * NH + h;
        e0 = ep[0 * NH]; e1 = ep[1 * NH]; e2 = ep[2 * NH]; e3 = ep[3 * NH];
    }

    for (int t = 0; t < T_STEPS; ++t) {
        // ---- rec = y(t) @ W_hh : 16 MFMA, A-frags straight from global ----
        const unsigned short* __restrict__ ysrc =
            ybuf + (size_t)(t & 1) * NB * NH + (size_t)(bbase + c) * NH + 8 * g;
        f32x4 ac0 = {0.f, 0.f, 0.f, 0.f};
        f32x4 ac1 = ac0, ac2 = ac0, ac3 = ac0;
#define MF(KB, AC)                                                           \
        AC = __builtin_amdgcn_mfma_f32_16x16x32_bf16(                        \
            *(const short8*)(ysrc + KB * 32), w##KB, AC, 0, 0, 0);
        MF(0, ac0)  MF(1, ac1)  MF(2, ac2)  MF(3, ac3)
        MF(4, ac0)  MF(5, ac1)  MF(6, ac2)  MF(7, ac3)
        MF(8, ac0)  MF(9, ac1)  MF(10, ac2) MF(11, ac3)
        MF(12, ac0) MF(13, ac1) MF(14, ac2) MF(15, ac3)
#undef MF
        const f32x4 recv = (ac0 + ac1) + (ac2 + ac3);

        // ---- elementwise update (reference order), f32 state in-lane ----
        // C/D layout: col = lane&15 = h, row = (lane>>4)*4 + reg = batch.
#define UPD(R, XR, YR, ER)                                                   \
        {                                                                    \
            const float rec = recv[R] + bhh_r;                               \
            const float inp = ER + gain * (rec + v_r * XR);                  \
            const float yt  = YR + hdt * (al_r * tanh_fast(inp)              \
                                          - om2_r * XR - g2_r * YR);         \
            XR = XR + hdt * yt;                                              \
            YR = yt;                                                         \
        }
        UPD(0, x0, y0, e0) UPD(1, x1, y1, e1) UPD(2, x2, y2, e2) UPD(3, x3, y3, e3)
#undef UPD

        const size_t obase = ((size_t)t * NB + bbase + 4 * g) * NH + h;

        if (t == T_STEPS - 1) {
            out[obase + 0 * NH] = x0; out[obase + 1 * NH] = x1;
            out[obase + 2 * NH] = x2; out[obase + 3 * NH] = x3;
            break;
        }

        // y(t+1) as bf16, agent-scope (write-through to coherence point)
        {
            unsigned short* ydst = ybuf + (size_t)((t + 1) & 1) * NB * NH
                                        + (size_t)(bbase + 4 * g) * NH + h;
            __hip_atomic_store(ydst + 0 * NH, f32_to_bf16(y0),
                               __ATOMIC_RELAXED, __HIP_MEMORY_SCOPE_AGENT);
            __hip_atomic_store(ydst + 1 * NH, f32_to_bf16(y1),
                               __ATOMIC_RELAXED, __HIP_MEMORY_SCOPE_AGENT);
            __hip_atomic_store(ydst + 2 * NH, f32_to_bf16(y2),
                               __ATOMIC_RELAXED, __HIP_MEMORY_SCOPE_AGENT);
            __hip_atomic_store(ydst + 3 * NH, f32_to_bf16(y3),
                               __ATOMIC_RELAXED, __HIP_MEMORY_SCOPE_AGENT);
        }

        // ---- group barrier: 4 WG flags, no RMW ----
        asm volatile("s_waitcnt vmcnt(0)" ::: "memory");  // y at coherence pt
        __syncthreads();                                  // all waves drained
        const unsigned tgt = (unsigned)(t + 1);
        if (tid == 0)
            __hip_atomic_store(flags + grp * 64 + wgi, tgt,
                               __ATOMIC_RELEASE, __HIP_MEMORY_SCOPE_AGENT);

        // overlap with poll window: x output + e[t+1] prefetch (private cells)
        out[obase + 0 * NH] = x0; out[obase + 1 * NH] = x1;
        out[obase + 2 * NH] = x2; out[obase + 3 * NH] = x3;
        e0 = out[obase + (size_t)NB * NH + 0 * NH];
        e1 = out[obase + (size_t)NB * NH + 1 * NH];
        e2 = out[obase + (size_t)NB * NH + 2 * NH];
        e3 = out[obase + (size_t)NB * NH + 3 * NH];

        if (tid == 0) {
            unsigned* fl = flags + grp * 64;
            for (;;) {
                const unsigned f0 = __hip_atomic_load(fl + 0, __ATOMIC_RELAXED, __HIP_MEMORY_SCOPE_AGENT);
                const unsigned f1 = __hip_atomic_load(fl + 1, __ATOMIC_RELAXED, __HIP_MEMORY_SCOPE_AGENT);
                const unsigned f2 = __hip_atomic_load(fl + 2, __ATOMIC_RELAXED, __HIP_MEMORY_SCOPE_AGENT);
                const unsigned f3 = __hip_atomic_load(fl + 3, __ATOMIC_RELAXED, __HIP_MEMORY_SCOPE_AGENT);
                if (f0 >= tgt && f1 >= tgt && f2 >= tgt && f3 >= tgt) break;
                __builtin_amdgcn_s_sleep(2);
            }
            __builtin_amdgcn_fence(__ATOMIC_ACQUIRE, "agent");  // L1/L2 inv
        }
        __syncthreads();   // releases WG; also compiler barrier for y loads
    }
}

// ---------------------------------------------------------------------------
extern "C" void kernel_launch(void* const* d_in, const int* in_sizes, int n_in,
                              void* d_out, int out_size, void* d_ws, size_t ws_size,
                              hipStream_t stream) {
    const float* inputs = (const float*)d_in[0];
    const float* W_ih   = (const float*)d_in[1];
    const float* b_ih   = (const float*)d_in[2];
    const float* W_hh   = (const float*)d_in[3];
    const float* b_hh   = (const float*)d_in[4];
    const float* alpha  = (const float*)d_in[5];
    const float* omega  = (const float*)d_in[6];
    const float* gamma  = (const float*)d_in[7];
    const float* v      = (const float*)d_in[8];
    float* out = (float*)d_out;

    unsigned* flags      = (unsigned*)d_ws;
    unsigned short* ybuf = (unsigned short*)((char*)d_ws + WS_YBUF_OFF);

    // zero flags + bf16 y slot 0 (d_ws re-poisoned every launch)
    hipMemsetAsync(d_ws, 0, WS_INIT_BYTES, stream);

    // ext = inputs @ W_ih + b_ih, written into d_out (overwritten step-by-step)
    ext_gemm_kernel<<<dim3(1024), dim3(256), 0, stream>>>(inputs, W_ih, b_ih, out);

    // sequential scan: 16 WGs (4 groups x 4 h-slices) x 512 threads
    horn_recurrent_kernel<<<dim3(NGRP * WGS_PER_GRP), dim3(512), 0, stream>>>(
        W_hh, b_hh, alpha, omega, gamma, v, out, ybuf, flags);
}